// Round 4
// baseline (28.401 us; speedup 1.0000x reference)
//
#include <hip/hip_runtime.h>

// out[i,j,k] = sum_h X[i+1,h]*X[j+1,h]*Wp[h,k] + b[k]
// (symmetrization cancels the antisymmetric d-terms; prod_term symmetric)
//
// R4: MFMA formulation. Two bf16 GEMMs C_k = A @ Bk^T with
//   A[m,h]  = bf16(X[m+1,h])          (M=384 padded, K=768)
//   Bk[n,h] = bf16(X[n+1,h] * W[h,k])
// Each block computes a 64x64 output tile for both k. Grid 6x6 = 36 blocks.

typedef __attribute__((ext_vector_type(8))) short frag_ab;  // 8 bf16
typedef __attribute__((ext_vector_type(4))) float f32x4;    // 4 f32 acc

constexpr int Hd   = 768;
constexpr int OUT  = 382;
constexpr int BT   = 64;        // block tile (rows and cols)
constexpr int HC   = 256;       // K chunk staged in LDS
constexpr int LSTR = HC + 8;    // LDS row stride in bf16 (264 -> 528 B: +4 banks/row)

static __device__ __forceinline__ unsigned short bfc(float f) {
  return __builtin_bit_cast(unsigned short, (__bf16)f);   // RNE f32->bf16
}

__global__ __launch_bounds__(256)
void pairhead_mfma(const float* __restrict__ X, const float* __restrict__ W,
                   const float* __restrict__ bias, float* __restrict__ out) {
  __shared__ unsigned short sA [BT * LSTR];   // 33.8 KB
  __shared__ unsigned short sB0[BT * LSTR];
  __shared__ unsigned short sB1[BT * LSTR];
  __shared__ float sW[Hd * 2];                // 6 KB, W rows interleaved (h,k)

  const int bm = blockIdx.y, bn = blockIdx.x;
  const int t  = threadIdx.x;
  const int w  = t >> 6, l = t & 63;
  const int wm = (w >> 1) * 32;               // wave's 32x32 quadrant
  const int wn = (w & 1) * 32;
  const int lr = l & 15;                      // fragment row/col within 16
  const int lg = l >> 4;                      // k-group (0..3)

  // preload all of W (1536 floats) into LDS
  for (int u = t; u < Hd * 2 / 4; u += 256)
    *reinterpret_cast<float4*>(&sW[u * 4]) = *reinterpret_cast<const float4*>(W + u * 4);

  f32x4 acc[2][2][2] = {};                    // [mi][ni][ch]

  for (int h0 = 0; h0 < Hd; h0 += HC) {
    __syncthreads();  // protects sW (1st iter) and sA/sB reuse (later iters)
    // stage: 64 rows x 64 float4 per operand-set; 16 iters per thread
    #pragma unroll 4
    for (int u = t; u < BT * (HC / 4); u += 256) {
      const int r = u >> 6, col = (u & 63) * 4;
      // A side
      const int gi = bm * BT + r;
      float4 xa = {};
      if (gi < 383) xa = *reinterpret_cast<const float4*>(X + (size_t)(gi + 1) * Hd + h0 + col);
      *reinterpret_cast<ushort4*>(&sA[r * LSTR + col]) =
          make_ushort4(bfc(xa.x), bfc(xa.y), bfc(xa.z), bfc(xa.w));
      // B side: fold W
      const int gj = bn * BT + r;
      float4 xb = {};
      if (gj < 383) xb = *reinterpret_cast<const float4*>(X + (size_t)(gj + 1) * Hd + h0 + col);
      const int cc = (h0 + col) * 2;
      const float4 wa = *reinterpret_cast<const float4*>(&sW[cc]);      // h..h+1, k=0,1
      const float4 wb = *reinterpret_cast<const float4*>(&sW[cc + 4]);  // h+2..h+3
      *reinterpret_cast<ushort4*>(&sB0[r * LSTR + col]) =
          make_ushort4(bfc(xb.x * wa.x), bfc(xb.y * wa.z), bfc(xb.z * wb.x), bfc(xb.w * wb.z));
      *reinterpret_cast<ushort4*>(&sB1[r * LSTR + col]) =
          make_ushort4(bfc(xb.x * wa.y), bfc(xb.y * wa.w), bfc(xb.z * wb.y), bfc(xb.w * wb.w));
    }
    __syncthreads();

    #pragma unroll
    for (int ks = 0; ks < HC / 32; ++ks) {
      const int kc = ks * 32 + lg * 8;
      const frag_ab a0  = *reinterpret_cast<const frag_ab*>(&sA [(wm + lr)      * LSTR + kc]);
      const frag_ab a1  = *reinterpret_cast<const frag_ab*>(&sA [(wm + 16 + lr) * LSTR + kc]);
      const frag_ab b00 = *reinterpret_cast<const frag_ab*>(&sB0[(wn + lr)      * LSTR + kc]);
      const frag_ab b01 = *reinterpret_cast<const frag_ab*>(&sB0[(wn + 16 + lr) * LSTR + kc]);
      const frag_ab b10 = *reinterpret_cast<const frag_ab*>(&sB1[(wn + lr)      * LSTR + kc]);
      const frag_ab b11 = *reinterpret_cast<const frag_ab*>(&sB1[(wn + 16 + lr) * LSTR + kc]);
      acc[0][0][0] = __builtin_amdgcn_mfma_f32_16x16x32_bf16(a0, b00, acc[0][0][0], 0, 0, 0);
      acc[0][1][0] = __builtin_amdgcn_mfma_f32_16x16x32_bf16(a0, b01, acc[0][1][0], 0, 0, 0);
      acc[1][0][0] = __builtin_amdgcn_mfma_f32_16x16x32_bf16(a1, b00, acc[1][0][0], 0, 0, 0);
      acc[1][1][0] = __builtin_amdgcn_mfma_f32_16x16x32_bf16(a1, b01, acc[1][1][0], 0, 0, 0);
      acc[0][0][1] = __builtin_amdgcn_mfma_f32_16x16x32_bf16(a0, b10, acc[0][0][1], 0, 0, 0);
      acc[0][1][1] = __builtin_amdgcn_mfma_f32_16x16x32_bf16(a0, b11, acc[0][1][1], 0, 0, 0);
      acc[1][0][1] = __builtin_amdgcn_mfma_f32_16x16x32_bf16(a1, b10, acc[1][0][1], 0, 0, 0);
      acc[1][1][1] = __builtin_amdgcn_mfma_f32_16x16x32_bf16(a1, b11, acc[1][1][1], 0, 0, 0);
    }
  }

  // epilogue: C/D layout col = lane&15, row = (lane>>4)*4 + reg
  const float b0 = bias[0], b1 = bias[1];
  #pragma unroll
  for (int mi = 0; mi < 2; ++mi)
    #pragma unroll
    for (int ni = 0; ni < 2; ++ni)
      #pragma unroll
      for (int r = 0; r < 4; ++r) {
        const int i = bm * BT + wm + mi * 16 + lg * 4 + r;
        const int j = bn * BT + wn + ni * 16 + lr;
        if (i < OUT && j < OUT)
          *reinterpret_cast<float2*>(&out[((size_t)i * OUT + j) * 2]) =
              make_float2(acc[mi][ni][0][r] + b0, acc[mi][ni][1][r] + b1);
      }
}

extern "C" void kernel_launch(void* const* d_in, const int* in_sizes, int n_in,
                              void* d_out, int out_size, void* d_ws, size_t ws_size,
                              hipStream_t stream) {
  const float* X    = (const float*)d_in[0];  // (1,384,768) fp32
  // d_in[1] = sequence_lengths (dead: output independent of it)
  const float* W    = (const float*)d_in[2];  // (1536,2) fp32; rows [0,768) = Wp
  const float* bias = (const float*)d_in[3];  // (2,)
  float* out = (float*)d_out;                 // (1,382,382,2) fp32

  pairhead_mfma<<<dim3(6, 6, 1), dim3(256, 1, 1), 0, stream>>>(X, W, bias, out);
}

// Round 5
// 20.889 us; speedup vs baseline: 1.3597x; 1.3597x over previous
//
#include <hip/hip_runtime.h>

// out[i,j,k] = sum_h X[i+1,h]*X[j+1,h]*Wp[h,k] + b[k]
// (symmetrization cancels the antisymmetric d-terms; prod_term symmetric)
//
// R5: latency-oriented MFMA. Prepass writes bf16 planes A, Y0=A.*w0, Y1=A.*w1
// to d_ws; GEMM runs ONE WAVE per 16x16 output tile (576 tiles, 288 blocks),
// fragments loaded straight from global (L2/LLC-resident), zero LDS, zero
// barriers -> maximal wave-level parallelism to hide memory latency.

typedef __attribute__((ext_vector_type(8))) short frag_ab;  // 8 bf16
typedef __attribute__((ext_vector_type(4))) float f32x4;

constexpr int Hd   = 768;
constexpr int OUT  = 382;
constexpr int NTI  = 24;                    // 16-tiles per dim (24*16=384)
constexpr size_t PLANE = (size_t)384 * Hd;  // elements per ws plane (bf16)
constexpr size_t WS_NEED = 3 * PLANE * sizeof(unsigned short);  // 1.77 MB

static __device__ __forceinline__ unsigned short bfc(float f) {
  return __builtin_bit_cast(unsigned short, (__bf16)f);   // RNE f32->bf16
}
static __device__ __forceinline__ unsigned int pk(unsigned short lo, unsigned short hi) {
  return (unsigned int)lo | ((unsigned int)hi << 16);
}

__global__ __launch_bounds__(128)
void prep_kernel(const float* __restrict__ X, const float* __restrict__ W,
                 unsigned short* __restrict__ ws) {
  const int gid = blockIdx.x * 128 + threadIdx.x;  // 0..36863
  const int m   = gid / 96;                        // row 0..383
  const int h0  = (gid - m * 96) * 8;              // col 0,8,..,760
  float x[8], wv[16];
  if (m < 383) {
    const float* xp = X + (size_t)(m + 1) * Hd + h0;
    float4 xa = *reinterpret_cast<const float4*>(xp);
    float4 xb = *reinterpret_cast<const float4*>(xp + 4);
    x[0]=xa.x; x[1]=xa.y; x[2]=xa.z; x[3]=xa.w;
    x[4]=xb.x; x[5]=xb.y; x[6]=xb.z; x[7]=xb.w;
    const float* wp = W + (size_t)h0 * 2;          // Wp rows interleaved (h,k)
    #pragma unroll
    for (int q = 0; q < 4; ++q) {
      float4 wq = *reinterpret_cast<const float4*>(wp + q * 4);
      wv[q*4+0]=wq.x; wv[q*4+1]=wq.y; wv[q*4+2]=wq.z; wv[q*4+3]=wq.w;
    }
  } else {  // pad row 383 with zeros
    #pragma unroll
    for (int q = 0; q < 8; ++q) x[q] = 0.f;
    #pragma unroll
    for (int q = 0; q < 16; ++q) wv[q] = 0.f;
  }
  unsigned short a[8], y0[8], y1[8];
  #pragma unroll
  for (int q = 0; q < 8; ++q) {
    a[q]  = bfc(x[q]);
    y0[q] = bfc(x[q] * wv[2*q]);
    y1[q] = bfc(x[q] * wv[2*q+1]);
  }
  const size_t off = (size_t)m * Hd + h0;
  uint4 pa = { pk(a[0],a[1]),  pk(a[2],a[3]),  pk(a[4],a[5]),  pk(a[6],a[7])  };
  uint4 p0 = { pk(y0[0],y0[1]),pk(y0[2],y0[3]),pk(y0[4],y0[5]),pk(y0[6],y0[7])};
  uint4 p1 = { pk(y1[0],y1[1]),pk(y1[2],y1[3]),pk(y1[4],y1[5]),pk(y1[6],y1[7])};
  *reinterpret_cast<uint4*>(ws + off)             = pa;
  *reinterpret_cast<uint4*>(ws + PLANE + off)     = p0;
  *reinterpret_cast<uint4*>(ws + 2 * PLANE + off) = p1;
}

__global__ __launch_bounds__(128)
void gemm_kernel(const unsigned short* __restrict__ ws,
                 const float* __restrict__ bias, float* __restrict__ out) {
  const int tile = blockIdx.x * 2 + (threadIdx.x >> 6);  // 0..575, one per wave
  const int mi = (tile * 2731) >> 16;                    // tile / 24 (exact for <576)
  const int nj = tile - mi * NTI;
  const int l  = threadIdx.x & 63;
  const int lr = l & 15;                                 // fragment row
  const int lg = l >> 4;                                 // k-group 0..3
  const unsigned short* Ap = ws +             (size_t)(mi*16 + lr) * Hd + lg*8;
  const unsigned short* B0 = ws + PLANE +     (size_t)(nj*16 + lr) * Hd + lg*8;
  const unsigned short* B1 = ws + 2*PLANE +   (size_t)(nj*16 + lr) * Hd + lg*8;

  f32x4 acc0 = {}, acc1 = {};
  #pragma unroll
  for (int ks = 0; ks < Hd / 32; ++ks) {                 // 24 k-slices
    const frag_ab a  = *reinterpret_cast<const frag_ab*>(Ap + ks*32);
    const frag_ab b0 = *reinterpret_cast<const frag_ab*>(B0 + ks*32);
    const frag_ab b1 = *reinterpret_cast<const frag_ab*>(B1 + ks*32);
    acc0 = __builtin_amdgcn_mfma_f32_16x16x32_bf16(a, b0, acc0, 0, 0, 0);
    acc1 = __builtin_amdgcn_mfma_f32_16x16x32_bf16(a, b1, acc1, 0, 0, 0);
  }

  const float b0v = bias[0], b1v = bias[1];
  #pragma unroll
  for (int r = 0; r < 4; ++r) {   // C/D: col = lane&15, row = (lane>>4)*4 + r
    const int i = mi * 16 + lg * 4 + r;
    const int j = nj * 16 + lr;
    if (i < OUT && j < OUT)
      *reinterpret_cast<float2*>(&out[((size_t)i * OUT + j) * 2]) =
          make_float2(acc0[r] + b0v, acc1[r] + b1v);
  }
}

// ---------- fallback (proven R2 kernel) if ws is too small ----------
constexpr int FT = 16, FNT = 24, FHC = 256, FSTR = FHC + 4;
__global__ __launch_bounds__(256)
void pairhead_fb(const float* __restrict__ X, const float* __restrict__ W,
                 const float* __restrict__ bias, float* __restrict__ out) {
  const int bi = blockIdx.y, bj = blockIdx.x;
  if (bj < bi) return;
  __shared__ float sx[FT][FSTR], sy[FT][FSTR], sw[FHC * 2];
  const int t = threadIdx.x, ti = t >> 4, tj = t & 15;
  const int i = bi * FT + ti, j = bj * FT + tj;
  float a0 = 0.f, a1 = 0.f;
  for (int h0 = 0; h0 < Hd; h0 += FHC) {
    __syncthreads();
    #pragma unroll
    for (int u = t; u < FT * FHC / 4; u += 256) {
      const int r = u >> 6, c = (u & 63) * 4;
      const int gi = bi * FT + r;
      float4 v = {}; if (gi < OUT) v = *reinterpret_cast<const float4*>(X + (size_t)(gi+1)*Hd + h0 + c);
      *reinterpret_cast<float4*>(&sx[r][c]) = v;
      const int gj = bj * FT + r;
      float4 w4 = {}; if (gj < OUT) w4 = *reinterpret_cast<const float4*>(X + (size_t)(gj+1)*Hd + h0 + c);
      *reinterpret_cast<float4*>(&sy[r][c]) = w4;
    }
    if (t < 128) *reinterpret_cast<float4*>(&sw[t*4]) = *reinterpret_cast<const float4*>(W + h0*2 + t*4);
    __syncthreads();
    #pragma unroll 16
    for (int c = 0; c < FHC; ++c) {
      const float p = sx[ti][c] * sy[tj][c];
      a0 += p * sw[2*c]; a1 += p * sw[2*c+1];
    }
  }
  if (i < OUT && j < OUT) {
    const float v0 = a0 + bias[0], v1 = a1 + bias[1];
    *reinterpret_cast<float2*>(&out[((size_t)i*OUT + j)*2]) = make_float2(v0, v1);
    if (bi != bj)
      *reinterpret_cast<float2*>(&out[((size_t)j*OUT + i)*2]) = make_float2(v0, v1);
  }
}

extern "C" void kernel_launch(void* const* d_in, const int* in_sizes, int n_in,
                              void* d_out, int out_size, void* d_ws, size_t ws_size,
                              hipStream_t stream) {
  const float* X    = (const float*)d_in[0];  // (1,384,768) fp32
  // d_in[1] = sequence_lengths (dead: output independent of it)
  const float* W    = (const float*)d_in[2];  // (1536,2) fp32; rows [0,768) = Wp
  const float* bias = (const float*)d_in[3];  // (2,)
  float* out = (float*)d_out;                 // (1,382,382,2) fp32

  if (ws_size >= WS_NEED) {
    unsigned short* ws = (unsigned short*)d_ws;
    prep_kernel<<<dim3(288, 1, 1), dim3(128, 1, 1), 0, stream>>>(X, W, ws);
    gemm_kernel<<<dim3(288, 1, 1), dim3(128, 1, 1), 0, stream>>>(ws, bias, out);
  } else {
    pairhead_fb<<<dim3(FNT, FNT, 1), dim3(256, 1, 1), 0, stream>>>(X, W, bias, out);
  }
}

// Round 6
// 16.510 us; speedup vs baseline: 1.7202x; 1.2652x over previous
//
#include <hip/hip_runtime.h>

// out[i,j,k] = sum_h X[i+1,h]*X[j+1,h]*Wp[h,k] + b[k]
// (symmetrization cancels the antisymmetric d-terms; prod_term symmetric)
//
// R6: single-dispatch fused MFMA. One wave per 16x16 output tile, split-K x2
// across the block's two waves (576 blocks x 128 thr = 1152 waves). Operands
// loaded fp32 straight from global (X is L2-resident, W is L1-resident),
// W folded in-register into the B operand, bf16 fragments built in-register.
// Cross-wave K-reduce via 2KB LDS. No prepass, no ws, no inter-dispatch
// dependency (avoids cross-XCD L2 writeback between dependent kernels).

typedef __attribute__((ext_vector_type(8))) short frag_ab;  // 8 bf16
typedef __attribute__((ext_vector_type(4))) float f32x4;

constexpr int Hd  = 768;
constexpr int OUT = 382;
constexpr int NTI = 24;     // 16-tiles per dim (24*16 = 384)

static __device__ __forceinline__ unsigned short bfc(float f) {
  return __builtin_bit_cast(unsigned short, (__bf16)f);   // RNE f32->bf16
}
static __device__ __forceinline__ frag_ab pack8(const float4& a, const float4& b) {
  frag_ab r;
  r[0] = (short)bfc(a.x); r[1] = (short)bfc(a.y);
  r[2] = (short)bfc(a.z); r[3] = (short)bfc(a.w);
  r[4] = (short)bfc(b.x); r[5] = (short)bfc(b.y);
  r[6] = (short)bfc(b.z); r[7] = (short)bfc(b.w);
  return r;
}

__global__ __launch_bounds__(128)
void fused_kernel(const float* __restrict__ X, const float* __restrict__ W,
                  const float* __restrict__ bias, float* __restrict__ out) {
  __shared__ float red[512];              // [k][r][lane] cross-wave reduce

  const int tile = blockIdx.x;            // 0..575
  const int mi = tile / NTI;
  const int nj = tile % NTI;
  const int half = threadIdx.x >> 6;      // K-split half (0 or 1)
  const int l  = threadIdx.x & 63;
  const int lr = l & 15;                  // fragment row
  const int lg = l >> 4;                  // k-group 0..3

  const int gi = mi * 16 + lr;            // A row this lane loads
  const int gj = nj * 16 + lr;            // B row this lane loads
  const float* Xi = X + (size_t)(gi + 1) * Hd;
  const float* Xj = X + (size_t)(gj + 1) * Hd;
  const bool vi = (gi < 383);             // X row gi+1 in bounds
  const bool vj = (gj < 383);

  f32x4 acc0 = {}, acc1 = {};
  #pragma unroll
  for (int s = 0; s < 12; ++s) {          // this wave's 12 of 24 k-slices
    const int h = (half * 12 + s) * 32 + lg * 8;
    float4 xa0 = {}, xa1 = {}, xb0 = {}, xb1 = {};
    if (vi) { xa0 = *reinterpret_cast<const float4*>(Xi + h);
              xa1 = *reinterpret_cast<const float4*>(Xi + h + 4); }
    if (vj) { xb0 = *reinterpret_cast<const float4*>(Xj + h);
              xb1 = *reinterpret_cast<const float4*>(Xj + h + 4); }
    // W rows h..h+7, interleaved (h,k): even floats k=0, odd floats k=1
    const float4 w0 = *reinterpret_cast<const float4*>(W + 2 * h);
    const float4 w1 = *reinterpret_cast<const float4*>(W + 2 * h + 4);
    const float4 w2 = *reinterpret_cast<const float4*>(W + 2 * h + 8);
    const float4 w3 = *reinterpret_cast<const float4*>(W + 2 * h + 12);

    const frag_ab a = pack8(xa0, xa1);
    const float4 b0lo = make_float4(xb0.x * w0.x, xb0.y * w0.z, xb0.z * w1.x, xb0.w * w1.z);
    const float4 b0hi = make_float4(xb1.x * w2.x, xb1.y * w2.z, xb1.z * w3.x, xb1.w * w3.z);
    const float4 b1lo = make_float4(xb0.x * w0.y, xb0.y * w0.w, xb0.z * w1.y, xb0.w * w1.w);
    const float4 b1hi = make_float4(xb1.x * w2.y, xb1.y * w2.w, xb1.z * w3.y, xb1.w * w3.w);
    const frag_ab b0 = pack8(b0lo, b0hi);
    const frag_ab b1 = pack8(b1lo, b1hi);

    acc0 = __builtin_amdgcn_mfma_f32_16x16x32_bf16(a, b0, acc0, 0, 0, 0);
    acc1 = __builtin_amdgcn_mfma_f32_16x16x32_bf16(a, b1, acc1, 0, 0, 0);
  }

  // cross-wave K-reduce: wave 1 parks its partials, wave 0 combines + stores
  if (half == 1) {
    #pragma unroll
    for (int r = 0; r < 4; ++r) {
      red[r * 64 + l]       = acc0[r];    // consecutive lanes -> consecutive banks
      red[256 + r * 64 + l] = acc1[r];
    }
  }
  __syncthreads();
  if (half == 0) {
    #pragma unroll
    for (int r = 0; r < 4; ++r) {
      acc0[r] += red[r * 64 + l];
      acc1[r] += red[256 + r * 64 + l];
    }
    const float b0v = bias[0], b1v = bias[1];
    #pragma unroll
    for (int r = 0; r < 4; ++r) {  // C/D: col = lane&15, row = (lane>>4)*4 + r
      const int i = mi * 16 + lg * 4 + r;
      const int j = nj * 16 + lr;
      if (i < OUT && j < OUT)
        *reinterpret_cast<float2*>(&out[((size_t)i * OUT + j) * 2]) =
            make_float2(acc0[r] + b0v, acc1[r] + b1v);
    }
  }
}

extern "C" void kernel_launch(void* const* d_in, const int* in_sizes, int n_in,
                              void* d_out, int out_size, void* d_ws, size_t ws_size,
                              hipStream_t stream) {
  const float* X    = (const float*)d_in[0];  // (1,384,768) fp32
  // d_in[1] = sequence_lengths (dead: output independent of it)
  const float* W    = (const float*)d_in[2];  // (1536,2) fp32; rows [0,768) = Wp
  const float* bias = (const float*)d_in[3];  // (2,)
  float* out = (float*)d_out;                 // (1,382,382,2) fp32

  fused_kernel<<<dim3(NTI * NTI, 1, 1), dim3(128, 1, 1), 0, stream>>>(X, W, bias, out);
}